// Round 7
// baseline (178.253 us; speedup 1.0000x reference)
//
#include <hip/hip_runtime.h>
#include <math.h>

#define M_DIM 24
#define N_DIM 12
#define H1    2880
#define HID   7200
#define H2    1152
#define DOUT  288
#define KGIN  (M_DIM + N_DIM)

// workspace layout (float offsets)
#define WS_PRIOR 0      // [24]
#define WS_DY    96     // [12]
#define WS_L1    128    // [2880]
#define WS_HNEW  3072   // [7200]
#define WS_L2    10304  // [1152]
#define WS_GI    11520  // [3*7200] gi partials (incl. bih)
#define WS_GH    33152  // [3*7200] gh partials (incl. bhh)

typedef float floatx4 __attribute__((ext_vector_type(4)));

__device__ __forceinline__ float wave_sum(float v) {
    #pragma unroll
    for (int o = 32; o; o >>= 1) v += __shfl_xor(v, o);
    return v;
}

// nontemporal 16B load (single-use weight streams: skip cache allocation)
__device__ __forceinline__ floatx4 ntload(const float4* p) {
    return __builtin_nontemporal_load((const floatx4*)p);
}

// ---- kernel 1: head (redundant per block) + l1 = relu(W1 @ kg_in + b1) ----
__global__ __launch_bounds__(256) void k_l1h(
        const float* __restrict__ yt, const float* __restrict__ F,
        const float* __restrict__ Hm, const float* __restrict__ post,
        const float* __restrict__ prior_old,
        const float* __restrict__ W1, const float* __restrict__ b1,
        float* __restrict__ ws) {
    __shared__ float s_prior[M_DIM];
    __shared__ float s_m1y[N_DIM];
    __shared__ float s_x[KGIN];
    __shared__ float s_dy[N_DIM];
    int t = threadIdx.x, lane = t & 63, w = t >> 6;

    if (t < M_DIM) {
        float acc = 0.f;
        #pragma unroll
        for (int j = 0; j < M_DIM; ++j) acc += F[t * M_DIM + j] * post[j];
        s_prior[t] = acc;
    }
    __syncthreads();
    if (t < N_DIM) {
        float acc = 0.f;
        #pragma unroll
        for (int j = 0; j < M_DIM; ++j) acc += Hm[t * M_DIM + j] * s_prior[j];
        s_m1y[t] = acc;
    }
    __syncthreads();
    if (w == 0) {
        float vx = 0.f;
        if (lane < M_DIM) vx = post[lane] - prior_old[lane];
        float nx = fmaxf(sqrtf(wave_sum(vx * vx)), 1e-12f);
        float vy = 0.f;
        if (lane < N_DIM) vy = yt[lane] - s_m1y[lane];
        float ny = fmaxf(sqrtf(wave_sum(vy * vy)), 1e-12f);
        if (lane < N_DIM) { s_x[lane] = vy / ny; s_dy[lane] = vy; }
        if (lane < M_DIM) s_x[N_DIM + lane] = vx / nx;
    }
    __syncthreads();

    if (blockIdx.x == 0) {
        if (t < M_DIM) ws[WS_PRIOR + t] = s_prior[t];
        if (t < N_DIM) ws[WS_DY + t] = s_dy[t];
    }

    int i = blockIdx.x * 4 + w;
    float acc = (lane < KGIN) ? W1[(size_t)i * KGIN + lane] * s_x[lane] : 0.f;
    acc = wave_sum(acc);
    if (lane == 0) ws[WS_L1 + i] = fmaxf(acc + b1[i], 0.f);
}

// ---- kernel 2: BOTH gate GEMVs, interleaved in groups of 8 blocks ----
// unroll 4 -> ~12 outstanding 16B loads/wave (576 B) for MLP past the
// latency*rate knee; launch_bounds(256,6) gives the allocator ~80 VGPR
// (24 waves/CU x 576 B ~= 13.8 KB/CU in flight).
__global__ __launch_bounds__(256, 6) void k_gates(
        const float* __restrict__ Wih, const float* __restrict__ Whh,
        const float* __restrict__ bih, const float* __restrict__ bhh,
        const float* __restrict__ hn, float* __restrict__ ws) {
    int t = threadIdx.x, lane = t & 63, w = t >> 6;
    int b = blockIdx.x;
    int g = b >> 3, r = b & 7;
    if ((g & 1) == 0) {
        // ---- gh: Whh @ hn ----
        int i = ((g >> 1) * 8 + r) * 4 + w;
        const float4* xh = (const float4*)hn;
        const float4* ur = (const float4*)(Whh + (size_t)i * HID);
        const float4* uz = (const float4*)(Whh + (size_t)(i + HID) * HID);
        const float4* un = (const float4*)(Whh + (size_t)(i + 2 * HID) * HID);
        float hr = 0.f, hz = 0.f, hh = 0.f;
        // HID/4 = 1800 = 28*64 + 8
        #pragma unroll 4
        for (int kk = 0; kk < 28; ++kk) {
            int k = kk * 64 + lane;
            float4 x = xh[k];
            floatx4 a = ntload(ur + k), bb = ntload(uz + k), c = ntload(un + k);
            hr += a.x * x.x + a.y * x.y + a.z * x.z + a.w * x.w;
            hz += bb.x * x.x + bb.y * x.y + bb.z * x.z + bb.w * x.w;
            hh += c.x * x.x + c.y * x.y + c.z * x.z + c.w * x.w;
        }
        if (lane < 8) {
            int k = 28 * 64 + lane;
            float4 x = xh[k];
            floatx4 a = ntload(ur + k), bb = ntload(uz + k), c = ntload(un + k);
            hr += a.x * x.x + a.y * x.y + a.z * x.z + a.w * x.w;
            hz += bb.x * x.x + bb.y * x.y + bb.z * x.z + bb.w * x.w;
            hh += c.x * x.x + c.y * x.y + c.z * x.z + c.w * x.w;
        }
        hr = wave_sum(hr); hz = wave_sum(hz); hh = wave_sum(hh);
        if (lane == 0) {
            ws[WS_GH + i]           = hr + bhh[i];
            ws[WS_GH + HID + i]     = hz + bhh[i + HID];
            ws[WS_GH + 2 * HID + i] = hh + bhh[i + 2 * HID];
        }
    } else {
        // ---- gi: Wih @ l1 ----
        int i = ((g >> 1) * 8 + r) * 4 + w;
        const float4* x1 = (const float4*)(ws + WS_L1);
        const float4* wr = (const float4*)(Wih + (size_t)i * H1);
        const float4* wz = (const float4*)(Wih + (size_t)(i + HID) * H1);
        const float4* wn = (const float4*)(Wih + (size_t)(i + 2 * HID) * H1);
        float ar = 0.f, az = 0.f, an = 0.f;
        // H1/4 = 720 = 11*64 + 16
        #pragma unroll 4
        for (int kk = 0; kk < 11; ++kk) {
            int k = kk * 64 + lane;
            float4 x = x1[k];
            floatx4 a = ntload(wr + k), bb = ntload(wz + k), c = ntload(wn + k);
            ar += a.x * x.x + a.y * x.y + a.z * x.z + a.w * x.w;
            az += bb.x * x.x + bb.y * x.y + bb.z * x.z + bb.w * x.w;
            an += c.x * x.x + c.y * x.y + c.z * x.z + c.w * x.w;
        }
        if (lane < 16) {
            int k = 11 * 64 + lane;
            float4 x = x1[k];
            floatx4 a = ntload(wr + k), bb = ntload(wz + k), c = ntload(wn + k);
            ar += a.x * x.x + a.y * x.y + a.z * x.z + a.w * x.w;
            az += bb.x * x.x + bb.y * x.y + bb.z * x.z + bb.w * x.w;
            an += c.x * x.x + c.y * x.y + c.z * x.z + c.w * x.w;
        }
        ar = wave_sum(ar); az = wave_sum(az); an = wave_sum(an);
        if (lane == 0) {
            ws[WS_GI + i]           = ar + bih[i];
            ws[WS_GI + HID + i]     = az + bih[i + HID];
            ws[WS_GI + 2 * HID + i] = an + bih[i + 2 * HID];
        }
    }
}

// ---- kernel 3: elementwise GRU combine -> h_new ----
__global__ __launch_bounds__(256) void k_comb(const float* __restrict__ hn,
                                              float* __restrict__ ws) {
    int i = blockIdx.x * 256 + threadIdx.x;
    if (i < HID) {
        float gr = ws[WS_GI + i] + ws[WS_GH + i];
        float gz = ws[WS_GI + HID + i] + ws[WS_GH + HID + i];
        float r = 1.f / (1.f + expf(-gr));
        float z = 1.f / (1.f + expf(-gz));
        float n = tanhf(ws[WS_GI + 2 * HID + i] + r * ws[WS_GH + 2 * HID + i]);
        ws[WS_HNEW + i] = (1.f - z) * n + z * hn[i];
    }
}

// ---- kernel 4: l2 = relu(W2 @ h_new + b2), one ROW per block ----
__global__ __launch_bounds__(256, 6) void k_l2(
        const float* __restrict__ W2, const float* __restrict__ b2,
        float* __restrict__ ws) {
    __shared__ float s_p[4];
    int t = threadIdx.x, lane = t & 63, w = t >> 6;
    int i = blockIdx.x;
    const float4* x4 = (const float4*)(ws + WS_HNEW);
    const float4* wr = (const float4*)(W2 + (size_t)i * HID);
    float acc = 0.f;
    // HID/4 = 1800 = 7*256 + 8
    #pragma unroll 4
    for (int kk = 0; kk < 7; ++kk) {
        int k = kk * 256 + t;
        float4 x = x4[k];
        floatx4 a = ntload(wr + k);
        acc += a.x * x.x + a.y * x.y + a.z * x.z + a.w * x.w;
    }
    if (t < 8) {
        int k = 7 * 256 + t;
        float4 x = x4[k];
        floatx4 a = ntload(wr + k);
        acc += a.x * x.x + a.y * x.y + a.z * x.z + a.w * x.w;
    }
    acc = wave_sum(acc);
    if (lane == 0) s_p[w] = acc;
    __syncthreads();
    if (t == 0)
        ws[WS_L2 + i] = fmaxf(s_p[0] + s_p[1] + s_p[2] + s_p[3] + b2[i], 0.f);
}

// ---- kernel 5: kg = W3 @ l2 + b3 fused with out = prior + kg @ dy ----
__global__ __launch_bounds__(768) void k_kg_out(
        const float* __restrict__ W3, const float* __restrict__ b3,
        const float* __restrict__ ws, float* __restrict__ out) {
    __shared__ float s_kg[N_DIM];
    int m = blockIdx.x;
    int t = threadIdx.x, lane = t & 63, w = t >> 6;  // w: 0..11
    int row = m * N_DIM + w;
    const float4* wr = (const float4*)(W3 + (size_t)row * H2);
    const float4* x4 = (const float4*)(ws + WS_L2);
    float acc = 0.f;
    // H2/4 = 288 = 4*64 + 32
    #pragma unroll
    for (int kk = 0; kk < 4; ++kk) {
        int k = kk * 64 + lane;
        float4 x = x4[k];
        floatx4 a = ntload(wr + k);
        acc += a.x * x.x + a.y * x.y + a.z * x.z + a.w * x.w;
    }
    if (lane < 32) {
        int k = 4 * 64 + lane;
        float4 x = x4[k];
        floatx4 a = ntload(wr + k);
        acc += a.x * x.x + a.y * x.y + a.z * x.z + a.w * x.w;
    }
    acc = wave_sum(acc);
    if (lane == 0) s_kg[w] = acc + b3[row];
    __syncthreads();
    if (t == 0) {
        float a = ws[WS_PRIOR + m];
        #pragma unroll
        for (int n = 0; n < N_DIM; ++n) a += s_kg[n] * ws[WS_DY + n];
        out[m] = a;
    }
}

extern "C" void kernel_launch(void* const* d_in, const int* in_sizes, int n_in,
                              void* d_out, int out_size, void* d_ws, size_t ws_size,
                              hipStream_t stream) {
    const float* yt        = (const float*)d_in[0];
    const float* F         = (const float*)d_in[1];
    const float* Hm        = (const float*)d_in[2];
    const float* post      = (const float*)d_in[3];
    const float* prior_old = (const float*)d_in[4];
    const float* hn        = (const float*)d_in[5];
    const float* W1        = (const float*)d_in[6];
    const float* b1        = (const float*)d_in[7];
    const float* Wih       = (const float*)d_in[8];
    const float* Whh       = (const float*)d_in[9];
    const float* bih       = (const float*)d_in[10];
    const float* bhh       = (const float*)d_in[11];
    const float* W2        = (const float*)d_in[12];
    const float* b2        = (const float*)d_in[13];
    const float* W3        = (const float*)d_in[14];
    const float* b3        = (const float*)d_in[15];
    float* out = (float*)d_out;
    float* ws  = (float*)d_ws;

    k_l1h   <<<H1 / 4, 256, 0, stream>>>(yt, F, Hm, post, prior_old, W1, b1, ws);
    k_gates <<<2 * (HID / 4), 256, 0, stream>>>(Wih, Whh, bih, bhh, hn, ws);
    k_comb  <<<(HID + 255) / 256, 256, 0, stream>>>(hn, ws);
    k_l2    <<<H2, 256, 0, stream>>>(W2, b2, ws);
    k_kg_out<<<M_DIM, 768, 0, stream>>>(W3, b3, ws, out);
}

// Round 8
// 157.022 us; speedup vs baseline: 1.1352x; 1.1352x over previous
//
#include <hip/hip_runtime.h>
#include <math.h>

#define M_DIM 24
#define N_DIM 12
#define H1    2880
#define HID   7200
#define H2    1152
#define DOUT  288
#define KGIN  (M_DIM + N_DIM)

// workspace layout (float offsets)
#define WS_PRIOR 0      // [24]
#define WS_DY    96     // [12]
#define WS_L1    128    // [2880]
#define WS_HNEW  3072   // [7200]
#define WS_L2    10304  // [1152]
#define WS_GI    11520  // [3*7200] gi partials (incl. bih)
#define WS_GH    33152  // [3*7200] gh half-0 partials (incl. bhh)
#define WS_GH2   54752  // [3*7200] gh half-1 partials

typedef float floatx4 __attribute__((ext_vector_type(4)));

__device__ __forceinline__ float wave_sum(float v) {
    #pragma unroll
    for (int o = 32; o; o >>= 1) v += __shfl_xor(v, o);
    return v;
}

// nontemporal 16B load — ONLY for the 871 MB single-use Wih/Whh streams.
// Small weights (W1/W2/W3) use plain loads so they can stay L3-resident
// across graph replays.
__device__ __forceinline__ floatx4 ntload(const float4* p) {
    return __builtin_nontemporal_load((const floatx4*)p);
}

// ---- kernel 1: head (redundant per block) + l1 = relu(W1 @ kg_in + b1) ----
__global__ __launch_bounds__(256) void k_l1h(
        const float* __restrict__ yt, const float* __restrict__ F,
        const float* __restrict__ Hm, const float* __restrict__ post,
        const float* __restrict__ prior_old,
        const float* __restrict__ W1, const float* __restrict__ b1,
        float* __restrict__ ws) {
    __shared__ float s_prior[M_DIM];
    __shared__ float s_m1y[N_DIM];
    __shared__ float s_x[KGIN];
    __shared__ float s_dy[N_DIM];
    int t = threadIdx.x, lane = t & 63, w = t >> 6;

    if (t < M_DIM) {
        float acc = 0.f;
        #pragma unroll
        for (int j = 0; j < M_DIM; ++j) acc += F[t * M_DIM + j] * post[j];
        s_prior[t] = acc;
    }
    __syncthreads();
    if (t < N_DIM) {
        float acc = 0.f;
        #pragma unroll
        for (int j = 0; j < M_DIM; ++j) acc += Hm[t * M_DIM + j] * s_prior[j];
        s_m1y[t] = acc;
    }
    __syncthreads();
    if (w == 0) {
        float vx = 0.f;
        if (lane < M_DIM) vx = post[lane] - prior_old[lane];
        float nx = fmaxf(sqrtf(wave_sum(vx * vx)), 1e-12f);
        float vy = 0.f;
        if (lane < N_DIM) vy = yt[lane] - s_m1y[lane];
        float ny = fmaxf(sqrtf(wave_sum(vy * vy)), 1e-12f);
        if (lane < N_DIM) { s_x[lane] = vy / ny; s_dy[lane] = vy; }
        if (lane < M_DIM) s_x[N_DIM + lane] = vx / nx;
    }
    __syncthreads();

    if (blockIdx.x == 0) {
        if (t < M_DIM) ws[WS_PRIOR + t] = s_prior[t];
        if (t < N_DIM) ws[WS_DY + t] = s_dy[t];
    }

    int i = blockIdx.x * 4 + w;
    float acc = (lane < KGIN) ? W1[(size_t)i * KGIN + lane] * s_x[lane] : 0.f;
    acc = wave_sum(acc);
    if (lane == 0) ws[WS_L1 + i] = fmaxf(acc + b1[i], 0.f);
}

// ---- kernel 2: gate GEMVs, R6 inner loop (unroll 2, bounds(256,8)) ----
// gh row-quads K-split into 2 blocks of 173 KB each -> uniform block sizes
// (gi = 138 KB) and half the end-of-kernel drain tail. Group-of-8 blocks
// alternate types 2:1 (gh:gh:gi) to balance the resident mix.
// 5400 blocks = 675 groups: g%3 in {0,1} -> gh, g%3==2 -> gi.
__global__ __launch_bounds__(256, 8) void k_gates(
        const float* __restrict__ Wih, const float* __restrict__ Whh,
        const float* __restrict__ bih, const float* __restrict__ bhh,
        const float* __restrict__ hn, float* __restrict__ ws) {
    int t = threadIdx.x, lane = t & 63, w = t >> 6;
    int b = blockIdx.x;
    int g = b >> 3, r = b & 7;
    int gm = g % 3;
    if (gm < 2) {
        // ---- gh: Whh @ hn, half-K per block ----
        int hb = ((g / 3) * 2 + gm) * 8 + r;          // [0,3600)
        int half = (hb >= 1800) ? 1 : 0;
        int Q = hb - half * 1800;                      // row quad [0,1800)
        int i = Q * 4 + w;
        int base = half * 900;                         // float4 K-offset
        const float4* xh = (const float4*)hn + base;
        const float4* ur = (const float4*)(Whh + (size_t)i * HID) + base;
        const float4* uz = (const float4*)(Whh + (size_t)(i + HID) * HID) + base;
        const float4* un = (const float4*)(Whh + (size_t)(i + 2 * HID) * HID) + base;
        float hr = 0.f, hz = 0.f, hh = 0.f;
        // 900 = 14*64 + 4
        #pragma unroll 2
        for (int kk = 0; kk < 14; ++kk) {
            int k = kk * 64 + lane;
            float4 x = xh[k];
            floatx4 a = ntload(ur + k), bb = ntload(uz + k), c = ntload(un + k);
            hr += a.x * x.x + a.y * x.y + a.z * x.z + a.w * x.w;
            hz += bb.x * x.x + bb.y * x.y + bb.z * x.z + bb.w * x.w;
            hh += c.x * x.x + c.y * x.y + c.z * x.z + c.w * x.w;
        }
        if (lane < 4) {
            int k = 14 * 64 + lane;
            float4 x = xh[k];
            floatx4 a = ntload(ur + k), bb = ntload(uz + k), c = ntload(un + k);
            hr += a.x * x.x + a.y * x.y + a.z * x.z + a.w * x.w;
            hz += bb.x * x.x + bb.y * x.y + bb.z * x.z + bb.w * x.w;
            hh += c.x * x.x + c.y * x.y + c.z * x.z + c.w * x.w;
        }
        hr = wave_sum(hr); hz = wave_sum(hz); hh = wave_sum(hh);
        if (lane == 0) {
            if (half) {
                ws[WS_GH2 + i]           = hr;
                ws[WS_GH2 + HID + i]     = hz;
                ws[WS_GH2 + 2 * HID + i] = hh;
            } else {
                ws[WS_GH + i]           = hr + bhh[i];
                ws[WS_GH + HID + i]     = hz + bhh[i + HID];
                ws[WS_GH + 2 * HID + i] = hh + bhh[i + 2 * HID];
            }
        }
    } else {
        // ---- gi: Wih @ l1, full K (H1/4 = 720 = 11*64 + 16) ----
        int i = ((g / 3) * 8 + r) * 4 + w;             // [0,7200)
        const float4* x1 = (const float4*)(ws + WS_L1);
        const float4* wr = (const float4*)(Wih + (size_t)i * H1);
        const float4* wz = (const float4*)(Wih + (size_t)(i + HID) * H1);
        const float4* wn = (const float4*)(Wih + (size_t)(i + 2 * HID) * H1);
        float ar = 0.f, az = 0.f, an = 0.f;
        #pragma unroll 2
        for (int kk = 0; kk < 11; ++kk) {
            int k = kk * 64 + lane;
            float4 x = x1[k];
            floatx4 a = ntload(wr + k), bb = ntload(wz + k), c = ntload(wn + k);
            ar += a.x * x.x + a.y * x.y + a.z * x.z + a.w * x.w;
            az += bb.x * x.x + bb.y * x.y + bb.z * x.z + bb.w * x.w;
            an += c.x * x.x + c.y * x.y + c.z * x.z + c.w * x.w;
        }
        if (lane < 16) {
            int k = 11 * 64 + lane;
            float4 x = x1[k];
            floatx4 a = ntload(wr + k), bb = ntload(wz + k), c = ntload(wn + k);
            ar += a.x * x.x + a.y * x.y + a.z * x.z + a.w * x.w;
            az += bb.x * x.x + bb.y * x.y + bb.z * x.z + bb.w * x.w;
            an += c.x * x.x + c.y * x.y + c.z * x.z + c.w * x.w;
        }
        ar = wave_sum(ar); az = wave_sum(az); an = wave_sum(an);
        if (lane == 0) {
            ws[WS_GI + i]           = ar + bih[i];
            ws[WS_GI + HID + i]     = az + bih[i + HID];
            ws[WS_GI + 2 * HID + i] = an + bih[i + 2 * HID];
        }
    }
}

// ---- kernel 3: elementwise GRU combine -> h_new ----
__global__ __launch_bounds__(256) void k_comb(const float* __restrict__ hn,
                                              float* __restrict__ ws) {
    int i = blockIdx.x * 256 + threadIdx.x;
    if (i < HID) {
        float ghr = ws[WS_GH + i]           + ws[WS_GH2 + i];
        float ghz = ws[WS_GH + HID + i]     + ws[WS_GH2 + HID + i];
        float ghn = ws[WS_GH + 2 * HID + i] + ws[WS_GH2 + 2 * HID + i];
        float gr = ws[WS_GI + i] + ghr;
        float gz = ws[WS_GI + HID + i] + ghz;
        float r = 1.f / (1.f + expf(-gr));
        float z = 1.f / (1.f + expf(-gz));
        float n = tanhf(ws[WS_GI + 2 * HID + i] + r * ghn);
        ws[WS_HNEW + i] = (1.f - z) * n + z * hn[i];
    }
}

// ---- kernel 4: l2 = relu(W2 @ h_new + b2), one ROW per block ----
// plain loads: W2 (33 MB) can stay L3-resident across graph replays.
__global__ __launch_bounds__(256, 8) void k_l2(
        const float* __restrict__ W2, const float* __restrict__ b2,
        float* __restrict__ ws) {
    __shared__ float s_p[4];
    int t = threadIdx.x, lane = t & 63, w = t >> 6;
    int i = blockIdx.x;
    const float4* x4 = (const float4*)(ws + WS_HNEW);
    const float4* wr = (const float4*)(W2 + (size_t)i * HID);
    float acc = 0.f;
    // HID/4 = 1800 = 7*256 + 8
    #pragma unroll 2
    for (int kk = 0; kk < 7; ++kk) {
        int k = kk * 256 + t;
        float4 x = x4[k];
        float4 a = wr[k];
        acc += a.x * x.x + a.y * x.y + a.z * x.z + a.w * x.w;
    }
    if (t < 8) {
        int k = 7 * 256 + t;
        float4 x = x4[k];
        float4 a = wr[k];
        acc += a.x * x.x + a.y * x.y + a.z * x.z + a.w * x.w;
    }
    acc = wave_sum(acc);
    if (lane == 0) s_p[w] = acc;
    __syncthreads();
    if (t == 0)
        ws[WS_L2 + i] = fmaxf(s_p[0] + s_p[1] + s_p[2] + s_p[3] + b2[i], 0.f);
}

// ---- kernel 5: kg = W3 @ l2 + b3 fused with out = prior + kg @ dy ----
// plain loads: W3 (1.3 MB) L3-resident across replays -> low-latency hits.
__global__ __launch_bounds__(768) void k_kg_out(
        const float* __restrict__ W3, const float* __restrict__ b3,
        const float* __restrict__ ws, float* __restrict__ out) {
    __shared__ float s_kg[N_DIM];
    int m = blockIdx.x;
    int t = threadIdx.x, lane = t & 63, w = t >> 6;  // w: 0..11
    int row = m * N_DIM + w;
    const float4* wr = (const float4*)(W3 + (size_t)row * H2);
    const float4* x4 = (const float4*)(ws + WS_L2);
    float acc = 0.f;
    // H2/4 = 288 = 4*64 + 32
    #pragma unroll
    for (int kk = 0; kk < 4; ++kk) {
        int k = kk * 64 + lane;
        float4 x = x4[k];
        float4 a = wr[k];
        acc += a.x * x.x + a.y * x.y + a.z * x.z + a.w * x.w;
    }
    if (lane < 32) {
        int k = 4 * 64 + lane;
        float4 x = x4[k];
        float4 a = wr[k];
        acc += a.x * x.x + a.y * x.y + a.z * x.z + a.w * x.w;
    }
    acc = wave_sum(acc);
    if (lane == 0) s_kg[w] = acc + b3[row];
    __syncthreads();
    if (t == 0) {
        float a = ws[WS_PRIOR + m];
        #pragma unroll
        for (int n = 0; n < N_DIM; ++n) a += s_kg[n] * ws[WS_DY + n];
        out[m] = a;
    }
}

extern "C" void kernel_launch(void* const* d_in, const int* in_sizes, int n_in,
                              void* d_out, int out_size, void* d_ws, size_t ws_size,
                              hipStream_t stream) {
    const float* yt        = (const float*)d_in[0];
    const float* F         = (const float*)d_in[1];
    const float* Hm        = (const float*)d_in[2];
    const float* post      = (const float*)d_in[3];
    const float* prior_old = (const float*)d_in[4];
    const float* hn        = (const float*)d_in[5];
    const float* W1        = (const float*)d_in[6];
    const float* b1        = (const float*)d_in[7];
    const float* Wih       = (const float*)d_in[8];
    const float* Whh       = (const float*)d_in[9];
    const float* bih       = (const float*)d_in[10];
    const float* bhh       = (const float*)d_in[11];
    const float* W2        = (const float*)d_in[12];
    const float* b2        = (const float*)d_in[13];
    const float* W3        = (const float*)d_in[14];
    const float* b3        = (const float*)d_in[15];
    float* out = (float*)d_out;
    float* ws  = (float*)d_ws;

    k_l1h   <<<H1 / 4, 256, 0, stream>>>(yt, F, Hm, post, prior_old, W1, b1, ws);
    // 3600 gh half-blocks + 1800 gi blocks = 5400 = 675 groups of 8
    k_gates <<<5400, 256, 0, stream>>>(Wih, Whh, bih, bhh, hn, ws);
    k_comb  <<<(HID + 255) / 256, 256, 0, stream>>>(hn, ws);
    k_l2    <<<H2, 256, 0, stream>>>(W2, b2, ws);
    k_kg_out<<<M_DIM, 768, 0, stream>>>(W3, b3, ws, out);
}